// Round 8
// baseline (83.931 us; speedup 1.0000x reference)
//
#include <hip/hip_runtime.h>
#include <math.h>

#define BLOCK 256
#define NB 4096          // value buckets; monotone bucketing => order-exact
#define CAP 64           // slots per bucket (max expected occupancy ~19 at N=16384)

__device__ __forceinline__ int bucket_of(float Tg) {
    int b = (int)((Tg + 6.0f) * ((float)NB / 12.0f));   // monotone in Tg
    return min(max(b, 0), NB - 1);
}

// K1: exp + bucket + direct slot write (rank from atomic). Last-arriving block
// computes the inclusive suffix scan of bucketE -> suffixE inline.
__global__ void __launch_bounds__(BLOCK)
surv_hist_scan(const float* __restrict__ theta, const float* __restrict__ T,
               int* __restrict__ counts, float* __restrict__ bucketE,
               float2* __restrict__ slots, float* __restrict__ ovTE,
               int* __restrict__ novf, int* __restrict__ done,
               float* __restrict__ suffixE, int n, int nblocks) {
    const int i = blockIdx.x * BLOCK + threadIdx.x;
    if (i < n) {
        const float Tg = T[i];
        const float E  = expf(theta[i]);
        const int b = bucket_of(Tg);
        const int r = atomicAdd(&counts[b], 1);
        atomicAdd(&bucketE[b], E);
        if (r < CAP) {
            slots[b * CAP + r] = make_float2(Tg, E);
        } else {                                  // exact overflow path (normally empty)
            const int o = atomicAdd(novf, 1);
            ovTE[2 * o] = Tg; ovTE[2 * o + 1] = E;
        }
    }

    // ---- last-block inline suffix scan ----
    __shared__ int lastFlag;
    __threadfence();
    __syncthreads();
    if (threadIdx.x == 0) {
        const int prev = atomicAdd(done, 1);
        lastFlag = (prev == nblocks - 1) ? 1 : 0;
    }
    __syncthreads();
    if (!lastFlag) return;

    __shared__ float ce[BLOCK];
    const int t = threadIdx.x;
    const int CH = NB / BLOCK;                    // 16 buckets/thread
    const int base = t * CH;
    float el[CH];
    float es = 0.f;
#pragma unroll
    for (int k = 0; k < CH; ++k) {                // coherent read via device-scope RMW
        el[k] = atomicAdd(&bucketE[base + k], 0.0f);
        es += el[k];
    }
    ce[t] = es;
    __syncthreads();
    for (int s = 1; s < BLOCK; s <<= 1) {         // Hillis-Steele suffix, 8 steps
        const float f = (t + s < BLOCK) ? ce[t + s] : 0.f;
        __syncthreads();
        ce[t] += f;
        __syncthreads();
    }
    float rs = ce[t] - es;                        // sum of chunks strictly after t
#pragma unroll
    for (int k = CH - 1; k >= 0; --k) { rs += el[k]; suffixE[base + k] = rs; }
    if (t == 0) suffixE[NB] = 0.f;
}

// K2: risk = suffixE[b+1] + exact in-bucket slot scan (+ overflow), term,
// block reduce, fused grid-final via done-counter.
__global__ void __launch_bounds__(BLOCK)
surv_risk_final(const float* __restrict__ theta, const float* __restrict__ T,
                const float* __restrict__ events,
                const int* __restrict__ counts, const float* __restrict__ suffixE,
                const float2* __restrict__ slots, const float* __restrict__ ovTE,
                const int* __restrict__ novf,
                float* __restrict__ acc, int* __restrict__ done2,
                float* __restrict__ out, int n, int nblocks) {
    __shared__ float red[BLOCK];
    const int tid = threadIdx.x;
    const int i = blockIdx.x * BLOCK + tid;
    float term = 0.f;
    if (i < n) {
        const float Ti = T[i];
        const int b = bucket_of(Ti);
        float risk = suffixE[b + 1];              // all strictly-higher buckets
        const int m = min(counts[b], CAP);
        const float2* sp = slots + (size_t)b * CAP;
        for (int p = 0; p < m; ++p) {             // exact in-bucket compare (incl. self)
            const float2 te = sp[p];
            risk += (te.x >= Ti) ? te.y : 0.f;
        }
        const int nv = *novf;                     // normally 0
        for (int o = 0; o < nv; ++o) {
            const float Tj = ovTE[2 * o];
            if (bucket_of(Tj) == b && Tj >= Ti) risk += ovTE[2 * o + 1];
        }
        term = (theta[i] - logf(risk)) * events[i];
    }
    red[tid] = term;
    __syncthreads();
    for (int s = BLOCK / 2; s > 0; s >>= 1) {
        if (tid < s) red[tid] += red[tid + s];
        __syncthreads();
    }
    if (tid == 0) {
        atomicAdd(acc, red[0]);
        __threadfence();
        const int prev = atomicAdd(done2, 1);
        if (prev == nblocks - 1) {
            const float total = atomicAdd(acc, 0.0f);   // coherent read-back
            out[0] = -total / (float)n;
        }
    }
}

// ---------- brute-force fallback (tiny ws / odd shapes) ----------
__global__ void surv_partial_bf(const float* __restrict__ theta, const float* __restrict__ T,
                                const float* __restrict__ events, float* __restrict__ bsum, int n) {
    __shared__ float red[BLOCK];
    const int tid = threadIdx.x;
    const int i = blockIdx.x * BLOCK + tid;
    float term = 0.f;
    if (i < n) {
        const float Ti = T[i];
        float risk = 0.f;
        for (int j = 0; j < n; ++j)
            risk += (T[j] >= Ti) ? expf(theta[j]) : 0.f;
        term = (theta[i] - logf(risk)) * events[i];
    }
    red[tid] = term;
    __syncthreads();
    for (int s = BLOCK / 2; s > 0; s >>= 1) {
        if (tid < s) red[tid] += red[tid + s];
        __syncthreads();
    }
    if (tid == 0) bsum[blockIdx.x] = red[0];
}

__global__ void surv_final_bf(const float* __restrict__ bsum, float* __restrict__ out,
                              int nblocks, int n) {
    float v = 0.f;
    for (int b = threadIdx.x; b < nblocks; b += 64) v += bsum[b];
    for (int off = 32; off > 0; off >>= 1) v += __shfl_down(v, off, 64);
    if (threadIdx.x == 0) out[0] = -v / (float)n;
}

extern "C" void kernel_launch(void* const* d_in, const int* in_sizes, int n_in,
                              void* d_out, int out_size, void* d_ws, size_t ws_size,
                              hipStream_t stream) {
    const float* theta  = (const float*)d_in[0];
    const float* T      = (const float*)d_in[1];
    const float* events = (const float*)d_in[2];
    float* out = (float*)d_out;
    const int n = in_sizes[0];                  // 16384
    const int nbi = (n + BLOCK - 1) / BLOCK;    // 64

    // ws layout (4B words). Zero region FIRST (single 32KB memset):
    //   counts[NB] bucketE[NB] acc done done2 novf  | suffixE[NB+1] pad |
    //   slots float2[NB*CAP] | ovTE[2n]
    const size_t zero_words = (size_t)2 * NB + 4;
    const size_t pre_slots  = zero_words + (NB + 1) + 1;      // +1 pad -> 8B aligned
    const size_t need = (pre_slots + (size_t)2 * NB * CAP + 2 * (size_t)n) * 4;

    if ((n % BLOCK) != 0 || ws_size < need) {
        float* bsum = (float*)d_ws;
        surv_partial_bf<<<nbi, BLOCK, 0, stream>>>(theta, T, events, bsum, n);
        surv_final_bf<<<1, 64, 0, stream>>>(bsum, out, nbi, n);
        return;
    }

    int*    counts  = (int*)d_ws;
    float*  bucketE = (float*)(counts + NB);
    float*  acc     = bucketE + NB;
    int*    done    = (int*)(acc + 1);
    int*    done2   = done + 1;
    int*    novf    = done2 + 1;
    float*  suffixE = (float*)(novf + 1);
    float2* slots   = (float2*)((float*)d_ws + pre_slots);
    float*  ovTE    = (float*)(slots + (size_t)NB * CAP);

    hipMemsetAsync(d_ws, 0, zero_words * 4, stream);  // counts+bucketE+acc+done+done2+novf
    surv_hist_scan<<<nbi, BLOCK, 0, stream>>>(theta, T, counts, bucketE, slots,
                                              ovTE, novf, done, suffixE, n, nbi);
    surv_risk_final<<<nbi, BLOCK, 0, stream>>>(theta, T, events, counts, suffixE,
                                               slots, ovTE, novf, acc, done2, out, n, nbi);
}